// Round 8
// baseline (422.836 us; speedup 1.0000x reference)
//
#include <hip/hip_runtime.h>

#define B_TOT   4096
#define T_STEPS 512
#define IN_F    5
#define D_FC    32
#define D_H     64
#define MB      16      // batches per block; DENSE M-tile: batch b = A-row b
#define NROW    16
#define ROWE    72      // f16 elems per row (64 h + 8 pad; 144B rows, 16B-aligned)

typedef _Float16 h8 __attribute__((ext_vector_type(8)));
typedef __fp16   h2 __attribute__((ext_vector_type(2)));
typedef float    f4 __attribute__((ext_vector_type(4)));

__device__ __forceinline__ float fexp2(float x) { return __builtin_amdgcn_exp2f(x); }
__device__ __forceinline__ float frcp(float x)  { return __builtin_amdgcn_rcpf(x); }

// one LSTM element, 8 trans ops (5 exp2 + 3 rcp), combined-rcp form:
//   i*g = (Eg-1) / ((1+Ei)(1+Eg));  o*tanh(c) = (Ec-1) / ((1+Eo)(1+Ec))
__device__ __forceinline__ void lstm_cell(
    float vi, float vf, float vg, float vo,
    float nbi, float nbf, float pbg, float nbo,
    float K1, float K2,
    float& cs, _Float16* dst)
{
    const float Ei = fexp2(fmaf(-K1, vi, nbi));
    const float Eg = fexp2(fmaf( K2, vg, pbg));
    const float Eo = fexp2(fmaf(-K1, vo, nbo));   // early: off the cs chain
    const float fg = frcp(1.0f + fexp2(fmaf(-K1, vf, nbf)));
    const float igg = (Eg - 1.0f) * frcp((1.0f + Ei) * (1.0f + Eg));
    cs = fmaf(fg, cs, igg);
    const float Ec = fexp2(K2 * cs);
    const float h  = (Ec - 1.0f) * frcp((1.0f + Eo) * (1.0f + Ec));
    *dst = (_Float16)h;
}

__global__ __launch_bounds__(512, 2) void lstm_mfma(
    const float* __restrict__ x,
    const float* __restrict__ W0,
    const float* __restrict__ b0,
    const float* __restrict__ W_ih,
    const float* __restrict__ W_hh,
    const float* __restrict__ b_ih,
    const float* __restrict__ b_hh,
    const float* __restrict__ Wo,
    const float* __restrict__ bo,
    float* __restrict__ out)
{
    // double-buffered h(t-1), f16: H[buf][batch-row][hidden]
    __shared__ __align__(16) _Float16 H[2][NROW][ROWE];

    const int tid  = threadIdx.x;
    const int lane = tid & 63;
    const int w    = tid >> 6;      // 0..7
    const int p    = w & 3;         // j-tile: owns hidden j in [p*16, p*16+16)
    const int eh   = w >> 2;        // elementwise half: acc regs {0,1} or {2,3}
    const int col  = lane & 15;
    const int quad = lane >> 4;
    const int bblk = blockIdx.x * MB;

    const float K1 = 1.4426950408889634f;   // log2(e)
    const float K2 = 2.8853900817779268f;   // 2*log2(e)

    // ---- resident W_hh B-fragments: FULL K (both halves duplicate MFMA work) ----
    h8 Bf[4][2];
    #pragma unroll
    for (int q = 0; q < 4; ++q) {
        const int row = q * 64 + p * 16 + col;
        #pragma unroll
        for (int c = 0; c < 2; ++c) {
            h8 f;
            #pragma unroll
            for (int jj = 0; jj < 8; ++jj) {
                const int k = c * 32 + quad * 8 + jj;
                f[jj] = (_Float16)W_hh[row * D_H + k];
            }
            Bf[q][c] = f;
        }
    }

    // ---- folded x-side weights: Weff = W_ih * W0 (256 x 5), K=32-padded frag ----
    h8 Bx[4];
    #pragma unroll
    for (int q = 0; q < 4; ++q) {
        #pragma unroll
        for (int jj = 0; jj < 8; ++jj) Bx[q][jj] = (_Float16)0.0f;
    }
    if (quad == 0) {
        #pragma unroll
        for (int q = 0; q < 4; ++q) {
            const int row = q * 64 + p * 16 + col;
            #pragma unroll
            for (int jj = 0; jj < IN_F; ++jj) {
                float s = 0.0f;
                #pragma unroll
                for (int m = 0; m < D_FC; ++m)
                    s = fmaf(W_ih[row * D_FC + m], W0[m * IN_F + jj], s);
                Bx[q][jj] = (_Float16)s;
            }
        }
    }

    // ---- folded bias, pre-scaled into the exp2 argument ----
    float sb[4];
    #pragma unroll
    for (int q = 0; q < 4; ++q) {
        const int row = q * 64 + p * 16 + col;
        float s = b_ih[row] + b_hh[row];
        #pragma unroll
        for (int m = 0; m < D_FC; ++m)
            s = fmaf(W_ih[row * D_FC + m], b0[m], s);
        sb[q] = s;
    }
    const float nbi = -K1 * sb[0];
    const float nbf = -K1 * sb[1];
    const float pbg =  K2 * sb[2];
    const float nbo = -K1 * sb[3];

    // ---- zero both LDS H buffers (h(-1)=0) ----
    for (int i = tid; i < 2 * NROW * ROWE; i += 512)
        ((_Float16*)H)[i] = (_Float16)0.0f;

    // ---- x feed: A-frag row = batch = col (halves duplicate; cache absorbs) ----
    const float* xb = x + (size_t)(bblk + col) * T_STEPS * IN_F;

    union AxU { h8 v; h2 pk[4]; };
    AxU Ax[2];
    #pragma unroll
    for (int jj = 0; jj < 8; ++jj) { Ax[0].v[jj] = (_Float16)0.0f; Ax[1].v[jj] = (_Float16)0.0f; }
    {   // Ax[0] = x(0)
        const f4 v0 = *(const f4*)xb;
        const float s0 = xb[4];
        Ax[0].pk[0] = __builtin_amdgcn_cvt_pkrtz(v0[0], v0[1]);
        Ax[0].pk[1] = __builtin_amdgcn_cvt_pkrtz(v0[2], v0[3]);
        Ax[0].pk[2] = __builtin_amdgcn_cvt_pkrtz(s0, 0.0f);
    }
    // prefetch buffers: xv[0]=x(1), xv[1]=x(2)
    f4 xv[2]; float x4[2];
    xv[0] = *(const f4*)(xb + IN_F);      x4[0] = xb[IN_F + 4];
    xv[1] = *(const f4*)(xb + 2 * IN_F);  x4[1] = xb[2 * IN_F + 4];

    f4 zk = {0.0f, 0.0f, 0.0f, 0.0f};
    // cell state: lane owns (batch = quad*4 + eh*2 + rl, j = p*16+col), rl = 0..1
    float cs0 = 0.0f, cs1 = 0.0f;

    __syncthreads();    // zero-init visible

    for (int it = 0; it < T_STEPS / 2; ++it) {
        #pragma unroll
        for (int u = 0; u < 2; ++u) {
            // h(t-1) A-fragments from buffer u
            const h8 A1 = *(const h8*)&H[u][col][quad * 8];
            const h8 A2 = *(const h8*)&H[u][col][32 + quad * 8];

            // pack next-step Ax while lgkm pending; then issue x(t+3) prefetch
            Ax[u ^ 1].pk[0] = __builtin_amdgcn_cvt_pkrtz(xv[u][0], xv[u][1]);
            Ax[u ^ 1].pk[1] = __builtin_amdgcn_cvt_pkrtz(xv[u][2], xv[u][3]);
            Ax[u ^ 1].pk[2] = __builtin_amdgcn_cvt_pkrtz(x4[u], 0.0f);
            {
                int tn = 2 * it + u + 3;
                tn = (tn < T_STEPS) ? tn : (T_STEPS - 1);
                const float* xp = xb + tn * IN_F;
                xv[u] = *(const f4*)xp;     // stays in flight across barriers
                x4[u] = xp[4];
            }

            // 12 MFMAs (duplicated across halves): x-MFMA first (register operands)
            f4 acc[4];
            #pragma unroll
            for (int q = 0; q < 4; ++q) {
                f4 a = __builtin_amdgcn_mfma_f32_16x16x32_f16(Ax[u].v, Bx[q], zk, 0, 0, 0);
                a = __builtin_amdgcn_mfma_f32_16x16x32_f16(A1, Bf[q][0], a, 0, 0, 0);
                a = __builtin_amdgcn_mfma_f32_16x16x32_f16(A2, Bf[q][1], a, 0, 0, 0);
                acc[q] = a;
            }

            // elementwise LSTM, my half's 2 rows — ALL acc indices literal,
            // no arrays, no pointer selects (avoids R7's scratch spill)
            if (eh == 0) {
                lstm_cell(acc[0][0], acc[1][0], acc[2][0], acc[3][0],
                          nbi, nbf, pbg, nbo, K1, K2,
                          cs0, &H[u ^ 1][quad * 4 + 0][p * 16 + col]);
                lstm_cell(acc[0][1], acc[1][1], acc[2][1], acc[3][1],
                          nbi, nbf, pbg, nbo, K1, K2,
                          cs1, &H[u ^ 1][quad * 4 + 1][p * 16 + col]);
            } else {
                lstm_cell(acc[0][2], acc[1][2], acc[2][2], acc[3][2],
                          nbi, nbf, pbg, nbo, K1, K2,
                          cs0, &H[u ^ 1][quad * 4 + 2][p * 16 + col]);
                lstm_cell(acc[0][3], acc[1][3], acc[2][3], acc[3][3],
                          nbi, nbf, pbg, nbo, K1, K2,
                          cs1, &H[u ^ 1][quad * 4 + 3][p * 16 + col]);
            }

            // single barrier WITHOUT vmcnt drain: H writes visible, x-prefetch in flight
            asm volatile("s_waitcnt lgkmcnt(0)" ::: "memory");
            __builtin_amdgcn_s_barrier();
            asm volatile("" ::: "memory");
        }
    }

    // ---- output head: h_last lives in H[0]; batch b at row b ----
    if (tid < MB) {
        float a = bo[0];
        #pragma unroll 8
        for (int j = 0; j < D_H; ++j)
            a = fmaf((float)H[0][tid][j], Wo[j], a);
        out[bblk + tid] = a;
    }
}

extern "C" void kernel_launch(void* const* d_in, const int* in_sizes, int n_in,
                              void* d_out, int out_size, void* d_ws, size_t ws_size,
                              hipStream_t stream) {
    const float* x    = (const float*)d_in[0];
    const float* W0   = (const float*)d_in[1];
    const float* b0   = (const float*)d_in[2];
    const float* W_ih = (const float*)d_in[3];
    const float* W_hh = (const float*)d_in[4];
    const float* b_ih = (const float*)d_in[5];
    const float* b_hh = (const float*)d_in[6];
    const float* Wo   = (const float*)d_in[7];
    const float* bo   = (const float*)d_in[8];
    float* out = (float*)d_out;

    hipLaunchKernelGGL(lstm_mfma, dim3(B_TOT / MB), dim3(512), 0, stream,
                       x, W0, b0, W_ih, W_hh, b_ih, b_hh, Wo, bo, out);
}

// Round 9
// 318.884 us; speedup vs baseline: 1.3260x; 1.3260x over previous
//
#include <hip/hip_runtime.h>

#define B_TOT   4096
#define T_STEPS 512
#define IN_F    5
#define D_FC    32
#define D_H     64
#define MB      16      // batches per block; DENSE M-tile: batch b = A-row b
#define NROW    16
#define ROWE    72      // f16 elems per row (64 h + 8 pad; 144B rows, 16B-aligned)

typedef _Float16 h8 __attribute__((ext_vector_type(8)));
typedef __fp16   h2 __attribute__((ext_vector_type(2)));
typedef float    f4 __attribute__((ext_vector_type(4)));

__device__ __forceinline__ float fexp2(float x) { return __builtin_amdgcn_exp2f(x); }
__device__ __forceinline__ float frcp(float x)  { return __builtin_amdgcn_rcpf(x); }

// one LSTM element, 8 trans ops (5 exp2 + 3 rcp), combined-rcp form
// (validated on HW in round 8: absmax 4.88e-4, same as 10-trans form):
//   i*g = (Eg-1) / ((1+Ei)(1+Eg));  o*tanh(c) = (Ec-1) / ((1+Eo)(1+Ec))
__device__ __forceinline__ void lstm_cell(
    float vi, float vf, float vg, float vo,
    float nbi, float nbf, float pbg, float nbo,
    float K1, float K2,
    float& cs, _Float16* dst)
{
    const float Ei = fexp2(fmaf(-K1, vi, nbi));
    const float Eg = fexp2(fmaf( K2, vg, pbg));
    const float Eo = fexp2(fmaf(-K1, vo, nbo));   // early: off the cs chain
    const float fg = frcp(1.0f + fexp2(fmaf(-K1, vf, nbf)));
    const float igg = (Eg - 1.0f) * frcp((1.0f + Ei) * (1.0f + Eg));
    cs = fmaf(fg, cs, igg);
    const float Ec = fexp2(K2 * cs);
    const float h  = (Ec - 1.0f) * frcp((1.0f + Eo) * (1.0f + Ec));
    *dst = (_Float16)h;
}

__global__ __launch_bounds__(256) void lstm_mfma(
    const float* __restrict__ x,
    const float* __restrict__ W0,
    const float* __restrict__ b0,
    const float* __restrict__ W_ih,
    const float* __restrict__ W_hh,
    const float* __restrict__ b_ih,
    const float* __restrict__ b_hh,
    const float* __restrict__ Wo,
    const float* __restrict__ bo,
    float* __restrict__ out)
{
    // double-buffered h(t-1), f16: H[buf][batch-row][hidden]
    __shared__ __align__(16) _Float16 H[2][NROW][ROWE];

    const int tid  = threadIdx.x;
    const int lane = tid & 63;
    const int w    = tid >> 6;      // wave id: owns hidden j in [w*16, w*16+16)
    const int col  = lane & 15;
    const int quad = lane >> 4;
    const int bblk = blockIdx.x * MB;

    const float K1 = 1.4426950408889634f;   // log2(e)
    const float K2 = 2.8853900817779268f;   // 2*log2(e)

    // ---- resident W_hh B-fragments: gate q, j = w*16+col, K = hidden 0..63 ----
    h8 Bf[4][2];
    #pragma unroll
    for (int q = 0; q < 4; ++q) {
        const int row = q * 64 + w * 16 + col;
        #pragma unroll
        for (int c = 0; c < 2; ++c) {
            h8 f;
            #pragma unroll
            for (int jj = 0; jj < 8; ++jj) {
                const int k = c * 32 + quad * 8 + jj;
                f[jj] = (_Float16)W_hh[row * D_H + k];
            }
            Bf[q][c] = f;
        }
    }

    // ---- folded x-side weights: Weff = W_ih * W0 (256 x 5), K=32-padded frag ----
    h8 Bx[4];
    #pragma unroll
    for (int q = 0; q < 4; ++q) {
        #pragma unroll
        for (int jj = 0; jj < 8; ++jj) Bx[q][jj] = (_Float16)0.0f;
    }
    if (quad == 0) {
        #pragma unroll
        for (int q = 0; q < 4; ++q) {
            const int row = q * 64 + w * 16 + col;
            #pragma unroll
            for (int jj = 0; jj < IN_F; ++jj) {
                float s = 0.0f;
                #pragma unroll
                for (int m = 0; m < D_FC; ++m)
                    s = fmaf(W_ih[row * D_FC + m], W0[m * IN_F + jj], s);
                Bx[q][jj] = (_Float16)s;
            }
        }
    }

    // ---- folded bias, pre-scaled into the exp2 argument ----
    float sb[4];
    #pragma unroll
    for (int q = 0; q < 4; ++q) {
        const int row = q * 64 + w * 16 + col;
        float s = b_ih[row] + b_hh[row];
        #pragma unroll
        for (int m = 0; m < D_FC; ++m)
            s = fmaf(W_ih[row * D_FC + m], b0[m], s);
        sb[q] = s;
    }
    const float nbi = -K1 * sb[0];
    const float nbf = -K1 * sb[1];
    const float pbg =  K2 * sb[2];
    const float nbo = -K1 * sb[3];

    // ---- zero both LDS H buffers (h(-1)=0) ----
    for (int i = tid; i < 2 * NROW * ROWE; i += 256)
        ((_Float16*)H)[i] = (_Float16)0.0f;

    // ---- x feed: A-frag row = batch = col (quads duplicate; cache absorbs) ----
    const float* xb = x + (size_t)(bblk + col) * T_STEPS * IN_F;

    union AxU { h8 v; h2 pk[4]; };
    AxU Ax[2];
    #pragma unroll
    for (int jj = 0; jj < 8; ++jj) { Ax[0].v[jj] = (_Float16)0.0f; Ax[1].v[jj] = (_Float16)0.0f; }
    {   // Ax[0] = x(0)
        const f4 v0 = *(const f4*)xb;
        const float s0 = xb[4];
        Ax[0].pk[0] = __builtin_amdgcn_cvt_pkrtz(v0[0], v0[1]);
        Ax[0].pk[1] = __builtin_amdgcn_cvt_pkrtz(v0[2], v0[3]);
        Ax[0].pk[2] = __builtin_amdgcn_cvt_pkrtz(s0, 0.0f);
    }
    // prefetch buffers: xv[0]=x(1), xv[1]=x(2)
    f4 xv[2]; float x4[2];
    xv[0] = *(const f4*)(xb + IN_F);      x4[0] = xb[IN_F + 4];
    xv[1] = *(const f4*)(xb + 2 * IN_F);  x4[1] = xb[2 * IN_F + 4];

    f4 zk = {0.0f, 0.0f, 0.0f, 0.0f};
    // cell state: lane owns (batch = quad*4 + r, j = w*16+col), r = 0..3
    float cs0 = 0.0f, cs1 = 0.0f, cs2 = 0.0f, cs3 = 0.0f;

    __syncthreads();    // zero-init visible

    for (int it = 0; it < T_STEPS / 2; ++it) {
        #pragma unroll
        for (int u = 0; u < 2; ++u) {
            // h(t-1) A-fragments from buffer u
            const h8 A1 = *(const h8*)&H[u][col][quad * 8];
            const h8 A2 = *(const h8*)&H[u][col][32 + quad * 8];

            // pack next-step Ax while lgkm pending; then issue x(t+3) prefetch
            Ax[u ^ 1].pk[0] = __builtin_amdgcn_cvt_pkrtz(xv[u][0], xv[u][1]);
            Ax[u ^ 1].pk[1] = __builtin_amdgcn_cvt_pkrtz(xv[u][2], xv[u][3]);
            Ax[u ^ 1].pk[2] = __builtin_amdgcn_cvt_pkrtz(x4[u], 0.0f);
            {
                int tn = 2 * it + u + 3;
                tn = (tn < T_STEPS) ? tn : (T_STEPS - 1);
                const float* xp = xb + tn * IN_F;
                xv[u] = *(const f4*)xp;     // stays in flight across barriers
                x4[u] = xp[4];
            }

            // 12 MFMAs, PHASE-MAJOR: x-phase (no LDS dep) issues during ds_read
            // wait; A1/A2 phases have deps 4 slots back -> latency hidden
            f4 acc[4];
            #pragma unroll
            for (int q = 0; q < 4; ++q)
                acc[q] = __builtin_amdgcn_mfma_f32_16x16x32_f16(Ax[u].v, Bx[q], zk, 0, 0, 0);
            #pragma unroll
            for (int q = 0; q < 4; ++q)
                acc[q] = __builtin_amdgcn_mfma_f32_16x16x32_f16(A1, Bf[q][0], acc[q], 0, 0, 0);
            #pragma unroll
            for (int q = 0; q < 4; ++q)
                acc[q] = __builtin_amdgcn_mfma_f32_16x16x32_f16(A2, Bf[q][1], acc[q], 0, 0, 0);

            // elementwise LSTM: 4 rows/lane, literal acc indices, named cs regs
            lstm_cell(acc[0][0], acc[1][0], acc[2][0], acc[3][0],
                      nbi, nbf, pbg, nbo, K1, K2,
                      cs0, &H[u ^ 1][quad * 4 + 0][w * 16 + col]);
            lstm_cell(acc[0][1], acc[1][1], acc[2][1], acc[3][1],
                      nbi, nbf, pbg, nbo, K1, K2,
                      cs1, &H[u ^ 1][quad * 4 + 1][w * 16 + col]);
            lstm_cell(acc[0][2], acc[1][2], acc[2][2], acc[3][2],
                      nbi, nbf, pbg, nbo, K1, K2,
                      cs2, &H[u ^ 1][quad * 4 + 2][w * 16 + col]);
            lstm_cell(acc[0][3], acc[1][3], acc[2][3], acc[3][3],
                      nbi, nbf, pbg, nbo, K1, K2,
                      cs3, &H[u ^ 1][quad * 4 + 3][w * 16 + col]);

            // single barrier WITHOUT vmcnt drain: H writes visible, x-prefetch in flight
            asm volatile("s_waitcnt lgkmcnt(0)" ::: "memory");
            __builtin_amdgcn_s_barrier();
            asm volatile("" ::: "memory");
        }
    }

    // ---- output head: h_last lives in H[0]; batch b at row b ----
    if (tid < MB) {
        float a = bo[0];
        #pragma unroll 8
        for (int j = 0; j < D_H; ++j)
            a = fmaf((float)H[0][tid][j], Wo[j], a);
        out[bblk + tid] = a;
    }
}

extern "C" void kernel_launch(void* const* d_in, const int* in_sizes, int n_in,
                              void* d_out, int out_size, void* d_ws, size_t ws_size,
                              hipStream_t stream) {
    const float* x    = (const float*)d_in[0];
    const float* W0   = (const float*)d_in[1];
    const float* b0   = (const float*)d_in[2];
    const float* W_ih = (const float*)d_in[3];
    const float* W_hh = (const float*)d_in[4];
    const float* b_ih = (const float*)d_in[5];
    const float* b_hh = (const float*)d_in[6];
    const float* Wo   = (const float*)d_in[7];
    const float* bo   = (const float*)d_in[8];
    float* out = (float*)d_out;

    hipLaunchKernelGGL(lstm_mfma, dim3(B_TOT / MB), dim3(256), 0, stream,
                       x, W0, b0, W_ih, W_hh, b_ih, b_hh, Wo, bo, out);
}

// Round 10
// 295.102 us; speedup vs baseline: 1.4328x; 1.0806x over previous
//
#include <hip/hip_runtime.h>

#define B_TOT   4096
#define T_STEPS 512
#define IN_F    5
#define D_FC    32
#define D_H     64
#define MB      16      // batches per block; DENSE M-tile: batch b = A-row b
#define NROW    16
#define ROWE    72      // f16 elems per row (64 h + 8 pad; 144B rows, 16B-aligned)

typedef _Float16 h8 __attribute__((ext_vector_type(8)));
typedef __fp16   h2 __attribute__((ext_vector_type(2)));
typedef float    f4 __attribute__((ext_vector_type(4)));
typedef float    f2 __attribute__((ext_vector_type(2)));

__device__ __forceinline__ float fexp2(float x) { return __builtin_amdgcn_exp2f(x); }
__device__ __forceinline__ float frcp(float x)  { return __builtin_amdgcn_rcpf(x); }

// LSTM cell-pair, packed-f32 form, 7 trans/cell (5 exp2 + 2 rcp):
//   cs' = [cs*(1+Ei)(1+Eg) + (Eg-1)(1+Ef)] / [(1+Ef)(1+Ei)(1+Eg)]
//   h   = (Ec-1) / ((1+Eo)(1+Ec)),  Ec = exp2(K2*cs')
// Full-rate ops on f32x2 (v_pk_*), trans scalar per component.
__device__ __forceinline__ void lstm_cell2(
    f2 vi, f2 vf, f2 vg, f2 vo,
    f2 nbi, f2 nbf, f2 pbg, f2 nbo, f2 mk1, f2 pk2, f2 one,
    f2& cs, _Float16* d0, _Float16* d1)
{
    const f2 aI = mk1 * vi + nbi;
    const f2 aF = mk1 * vf + nbf;
    const f2 aG = pk2 * vg + pbg;
    const f2 aO = mk1 * vo + nbo;
    f2 Ei, Ef, Eg, Eo;
    Ei[0] = fexp2(aI[0]); Ei[1] = fexp2(aI[1]);
    Eg[0] = fexp2(aG[0]); Eg[1] = fexp2(aG[1]);
    Eo[0] = fexp2(aO[0]); Eo[1] = fexp2(aO[1]);   // early: off the cs chain
    Ef[0] = fexp2(aF[0]); Ef[1] = fexp2(aF[1]);
    const f2 pI = one + Ei;
    const f2 pF = one + Ef;
    const f2 pG = one + Eg;
    const f2 pO = one + Eo;
    const f2 mIG = pI * pG;
    const f2 num = cs * mIG + (Eg - one) * pF;
    const f2 den = mIG * pF;
    f2 r;
    r[0] = frcp(den[0]); r[1] = frcp(den[1]);
    cs = num * r;
    const f2 aC = pk2 * cs;
    f2 Ec;
    Ec[0] = fexp2(aC[0]); Ec[1] = fexp2(aC[1]);
    const f2 mOC = pO * (one + Ec);
    f2 r2;
    r2[0] = frcp(mOC[0]); r2[1] = frcp(mOC[1]);
    const f2 h = (Ec - one) * r2;
    *d0 = (_Float16)h[0];
    *d1 = (_Float16)h[1];
}

__global__ __launch_bounds__(256) void lstm_mfma(
    const float* __restrict__ x,
    const float* __restrict__ W0,
    const float* __restrict__ b0,
    const float* __restrict__ W_ih,
    const float* __restrict__ W_hh,
    const float* __restrict__ b_ih,
    const float* __restrict__ b_hh,
    const float* __restrict__ Wo,
    const float* __restrict__ bo,
    float* __restrict__ out)
{
    // double-buffered h(t-1), f16: H[buf][batch-row][hidden]
    __shared__ __align__(16) _Float16 H[2][NROW][ROWE];

    const int tid  = threadIdx.x;
    const int lane = tid & 63;
    const int w    = tid >> 6;      // wave id: owns hidden j in [w*16, w*16+16)
    const int col  = lane & 15;
    const int quad = lane >> 4;
    const int bblk = blockIdx.x * MB;

    const float K1 = 1.4426950408889634f;   // log2(e)
    const float K2 = 2.8853900817779268f;   // 2*log2(e)

    // ---- resident W_hh B-fragments: gate q, j = w*16+col, K = hidden 0..63 ----
    h8 Bf[4][2];
    #pragma unroll
    for (int q = 0; q < 4; ++q) {
        const int row = q * 64 + w * 16 + col;
        #pragma unroll
        for (int c = 0; c < 2; ++c) {
            h8 f;
            #pragma unroll
            for (int jj = 0; jj < 8; ++jj) {
                const int k = c * 32 + quad * 8 + jj;
                f[jj] = (_Float16)W_hh[row * D_H + k];
            }
            Bf[q][c] = f;
        }
    }

    // ---- folded x-side weights: Weff = W_ih * W0 (256 x 5), K=32-padded frag ----
    h8 Bx[4];
    #pragma unroll
    for (int q = 0; q < 4; ++q) {
        #pragma unroll
        for (int jj = 0; jj < 8; ++jj) Bx[q][jj] = (_Float16)0.0f;
    }
    if (quad == 0) {
        #pragma unroll
        for (int q = 0; q < 4; ++q) {
            const int row = q * 64 + w * 16 + col;
            #pragma unroll
            for (int jj = 0; jj < IN_F; ++jj) {
                float s = 0.0f;
                #pragma unroll
                for (int m = 0; m < D_FC; ++m)
                    s = fmaf(W_ih[row * D_FC + m], W0[m * IN_F + jj], s);
                Bx[q][jj] = (_Float16)s;
            }
        }
    }

    // ---- folded bias, pre-scaled into the exp2 argument ----
    float sb[4];
    #pragma unroll
    for (int q = 0; q < 4; ++q) {
        const int row = q * 64 + w * 16 + col;
        float s = b_ih[row] + b_hh[row];
        #pragma unroll
        for (int m = 0; m < D_FC; ++m)
            s = fmaf(W_ih[row * D_FC + m], b0[m], s);
        sb[q] = s;
    }
    // broadcast f2 constants (hoisted; VGPR budget is free at 1 block/CU)
    const f2 nbi = { -K1 * sb[0], -K1 * sb[0] };
    const f2 nbf = { -K1 * sb[1], -K1 * sb[1] };
    const f2 pbg = {  K2 * sb[2],  K2 * sb[2] };
    const f2 nbo = { -K1 * sb[3], -K1 * sb[3] };
    const f2 mk1 = { -K1, -K1 };
    const f2 pk2 = {  K2,  K2 };
    const f2 one = { 1.0f, 1.0f };

    // ---- zero both LDS H buffers (h(-1)=0) ----
    for (int i = tid; i < 2 * NROW * ROWE; i += 256)
        ((_Float16*)H)[i] = (_Float16)0.0f;

    // ---- x feed: A-frag row = batch = col (quads duplicate; cache absorbs) ----
    const float* xb = x + (size_t)(bblk + col) * T_STEPS * IN_F;

    union AxU { h8 v; h2 pk[4]; };
    AxU Ax[2];
    #pragma unroll
    for (int jj = 0; jj < 8; ++jj) { Ax[0].v[jj] = (_Float16)0.0f; Ax[1].v[jj] = (_Float16)0.0f; }
    {   // Ax[0] = x(0)
        const f4 v0 = *(const f4*)xb;
        const float s0 = xb[4];
        Ax[0].pk[0] = __builtin_amdgcn_cvt_pkrtz(v0[0], v0[1]);
        Ax[0].pk[1] = __builtin_amdgcn_cvt_pkrtz(v0[2], v0[3]);
        Ax[0].pk[2] = __builtin_amdgcn_cvt_pkrtz(s0, 0.0f);
    }
    // prefetch buffers: xv[0]=x(1), xv[1]=x(2)
    f4 xv[2]; float x4[2];
    xv[0] = *(const f4*)(xb + IN_F);      x4[0] = xb[IN_F + 4];
    xv[1] = *(const f4*)(xb + 2 * IN_F);  x4[1] = xb[2 * IN_F + 4];

    f4 zk = {0.0f, 0.0f, 0.0f, 0.0f};
    // cell state: lane owns (batch = quad*4 + r, j = w*16+col); pairs {0,1},{2,3}
    f2 cs01 = {0.0f, 0.0f}, cs23 = {0.0f, 0.0f};

    __syncthreads();    // zero-init visible

    for (int it = 0; it < T_STEPS / 2; ++it) {
        #pragma unroll
        for (int u = 0; u < 2; ++u) {
            // h(t-1) A-fragments from buffer u
            const h8 A1 = *(const h8*)&H[u][col][quad * 8];
            const h8 A2 = *(const h8*)&H[u][col][32 + quad * 8];

            // pack next-step Ax while lgkm pending; then issue x(t+3) prefetch
            Ax[u ^ 1].pk[0] = __builtin_amdgcn_cvt_pkrtz(xv[u][0], xv[u][1]);
            Ax[u ^ 1].pk[1] = __builtin_amdgcn_cvt_pkrtz(xv[u][2], xv[u][3]);
            Ax[u ^ 1].pk[2] = __builtin_amdgcn_cvt_pkrtz(x4[u], 0.0f);
            {
                int tn = 2 * it + u + 3;
                tn = (tn < T_STEPS) ? tn : (T_STEPS - 1);
                const float* xp = xb + tn * IN_F;
                xv[u] = *(const f4*)xp;     // stays in flight across barriers
                x4[u] = xp[4];
            }

            // 12 MFMAs, PHASE-MAJOR: x-phase (no LDS dep) issues during ds_read wait
            f4 acc[4];
            #pragma unroll
            for (int q = 0; q < 4; ++q)
                acc[q] = __builtin_amdgcn_mfma_f32_16x16x32_f16(Ax[u].v, Bx[q], zk, 0, 0, 0);
            #pragma unroll
            for (int q = 0; q < 4; ++q)
                acc[q] = __builtin_amdgcn_mfma_f32_16x16x32_f16(A1, Bf[q][0], acc[q], 0, 0, 0);
            #pragma unroll
            for (int q = 0; q < 4; ++q)
                acc[q] = __builtin_amdgcn_mfma_f32_16x16x32_f16(A2, Bf[q][1], acc[q], 0, 0, 0);

            // elementwise LSTM, packed cell-pairs; all acc indices literal
            lstm_cell2((f2){acc[0][0], acc[0][1]}, (f2){acc[1][0], acc[1][1]},
                       (f2){acc[2][0], acc[2][1]}, (f2){acc[3][0], acc[3][1]},
                       nbi, nbf, pbg, nbo, mk1, pk2, one, cs01,
                       &H[u ^ 1][quad * 4 + 0][w * 16 + col],
                       &H[u ^ 1][quad * 4 + 1][w * 16 + col]);
            lstm_cell2((f2){acc[0][2], acc[0][3]}, (f2){acc[1][2], acc[1][3]},
                       (f2){acc[2][2], acc[2][3]}, (f2){acc[3][2], acc[3][3]},
                       nbi, nbf, pbg, nbo, mk1, pk2, one, cs23,
                       &H[u ^ 1][quad * 4 + 2][w * 16 + col],
                       &H[u ^ 1][quad * 4 + 3][w * 16 + col]);

            // single barrier WITHOUT vmcnt drain: H writes visible, x-prefetch in flight
            asm volatile("s_waitcnt lgkmcnt(0)" ::: "memory");
            __builtin_amdgcn_s_barrier();
            asm volatile("" ::: "memory");
        }
    }

    // ---- output head: h_last lives in H[0]; batch b at row b ----
    if (tid < MB) {
        float a = bo[0];
        #pragma unroll 8
        for (int j = 0; j < D_H; ++j)
            a = fmaf((float)H[0][tid][j], Wo[j], a);
        out[bblk + tid] = a;
    }
}

extern "C" void kernel_launch(void* const* d_in, const int* in_sizes, int n_in,
                              void* d_out, int out_size, void* d_ws, size_t ws_size,
                              hipStream_t stream) {
    const float* x    = (const float*)d_in[0];
    const float* W0   = (const float*)d_in[1];
    const float* b0   = (const float*)d_in[2];
    const float* W_ih = (const float*)d_in[3];
    const float* W_hh = (const float*)d_in[4];
    const float* b_ih = (const float*)d_in[5];
    const float* b_hh = (const float*)d_in[6];
    const float* Wo   = (const float*)d_in[7];
    const float* bo   = (const float*)d_in[8];
    float* out = (float*)d_out;

    hipLaunchKernelGGL(lstm_mfma, dim3(B_TOT / MB), dim3(256), 0, stream,
                       x, W0, b0, W_ih, W_hh, b_ih, b_hh, Wo, bo, out);
}

// Round 11
// 283.383 us; speedup vs baseline: 1.4921x; 1.0414x over previous
//
#include <hip/hip_runtime.h>

#define B_TOT   4096
#define T_STEPS 512
#define IN_F    5
#define D_FC    32
#define D_H     64
#define MB      16      // batches per block; DENSE M-tile: batch b = A-row b
#define NROW    16
#define ROWE    72      // f16 elems per row (64 h + 8 pad; 144B rows, 16B-aligned)

typedef _Float16 h8 __attribute__((ext_vector_type(8)));
typedef __fp16   h2 __attribute__((ext_vector_type(2)));
typedef float    f4 __attribute__((ext_vector_type(4)));
typedef float    f2 __attribute__((ext_vector_type(2)));

__device__ __forceinline__ float fexp2(float x) { return __builtin_amdgcn_exp2f(x); }
__device__ __forceinline__ float frcp(float x)  { return __builtin_amdgcn_rcpf(x); }

// LSTM cell-quad, packed-f32. Weights/bias are PRE-SCALED so acc IS the exp2 arg:
//   gates i,f,o scaled by -log2(e); gate g by 2*log2(e).
//   Ei=exp2(acc_i) etc;  cs' = cs/(1+Ef) + (Eg-1)/((1+Ei)(1+Eg))
//   h = (Ec-1)/((1+Eo)(1+Ec)), Ec = exp2(K2*cs')
// 7 trans/cell (5 exp2 + 2 rcp); all 16 exp2 issued up front (trans pipe fill).
__device__ __forceinline__ void lstm_cell4(
    f2 iA, f2 fA, f2 gA, f2 oA,       // pair {0,1} exp2 args
    f2 iB, f2 fB, f2 gB, f2 oB,       // pair {2,3} exp2 args
    f2 pk2, f2 one,
    f2& csA, f2& csB,
    _Float16* d0, _Float16* d1, _Float16* d2, _Float16* d3)
{
    f2 EiA, EfA, EgA, EoA, EiB, EfB, EgB, EoB;
    EiA[0]=fexp2(iA[0]); EiA[1]=fexp2(iA[1]);
    EgA[0]=fexp2(gA[0]); EgA[1]=fexp2(gA[1]);
    EfA[0]=fexp2(fA[0]); EfA[1]=fexp2(fA[1]);
    EoA[0]=fexp2(oA[0]); EoA[1]=fexp2(oA[1]);
    EiB[0]=fexp2(iB[0]); EiB[1]=fexp2(iB[1]);
    EgB[0]=fexp2(gB[0]); EgB[1]=fexp2(gB[1]);
    EfB[0]=fexp2(fB[0]); EfB[1]=fexp2(fB[1]);
    EoB[0]=fexp2(oB[0]); EoB[1]=fexp2(oB[1]);

    const f2 pIA = one + EiA, pFA = one + EfA, pGA = one + EgA, pOA = one + EoA;
    const f2 pIB = one + EiB, pFB = one + EfB, pGB = one + EgB, pOB = one + EoB;

    const f2 mIGA = pIA * pGA;
    const f2 mIGB = pIB * pGB;
    const f2 numA = csA * mIGA + (EgA - one) * pFA;
    const f2 numB = csB * mIGB + (EgB - one) * pFB;
    const f2 denA = mIGA * pFA;
    const f2 denB = mIGB * pFB;
    f2 rA, rB;
    rA[0] = frcp(denA[0]); rA[1] = frcp(denA[1]);
    rB[0] = frcp(denB[0]); rB[1] = frcp(denB[1]);
    csA = numA * rA;
    csB = numB * rB;
    const f2 aCA = pk2 * csA;
    const f2 aCB = pk2 * csB;
    f2 EcA, EcB;
    EcA[0]=fexp2(aCA[0]); EcA[1]=fexp2(aCA[1]);
    EcB[0]=fexp2(aCB[0]); EcB[1]=fexp2(aCB[1]);
    const f2 mOCA = pOA * (one + EcA);
    const f2 mOCB = pOB * (one + EcB);
    f2 r2A, r2B;
    r2A[0] = frcp(mOCA[0]); r2A[1] = frcp(mOCA[1]);
    r2B[0] = frcp(mOCB[0]); r2B[1] = frcp(mOCB[1]);
    const f2 hA = (EcA - one) * r2A;
    const f2 hB = (EcB - one) * r2B;
    *d0 = (_Float16)hA[0];
    *d1 = (_Float16)hA[1];
    *d2 = (_Float16)hB[0];
    *d3 = (_Float16)hB[1];
}

__global__ __launch_bounds__(256) void lstm_mfma(
    const float* __restrict__ x,
    const float* __restrict__ W0,
    const float* __restrict__ b0,
    const float* __restrict__ W_ih,
    const float* __restrict__ W_hh,
    const float* __restrict__ b_ih,
    const float* __restrict__ b_hh,
    const float* __restrict__ Wo,
    const float* __restrict__ bo,
    float* __restrict__ out)
{
    // double-buffered h(t-1), f16: H[buf][batch-row][hidden]
    __shared__ __align__(16) _Float16 H[2][NROW][ROWE];

    const int tid  = threadIdx.x;
    const int lane = tid & 63;
    const int w    = tid >> 6;      // wave id: owns hidden j in [w*16, w*16+16)
    const int col  = lane & 15;
    const int quad = lane >> 4;
    const int bblk = blockIdx.x * MB;

    const float K1 = 1.4426950408889634f;   // log2(e)
    const float K2 = 2.8853900817779268f;   // 2*log2(e)
    // per-gate pre-scale: i,f,o -> -log2(e); g -> +2*log2(e)
    const float SC[4] = { -K1, -K1, K2, -K1 };

    // ---- resident W_hh B-fragments, PRE-SCALED per gate ----
    h8 Bf[4][2];
    #pragma unroll
    for (int q = 0; q < 4; ++q) {
        const int row = q * 64 + w * 16 + col;
        #pragma unroll
        for (int c = 0; c < 2; ++c) {
            h8 f;
            #pragma unroll
            for (int jj = 0; jj < 8; ++jj) {
                const int k = c * 32 + quad * 8 + jj;
                f[jj] = (_Float16)(W_hh[row * D_H + k] * SC[q]);
            }
            Bf[q][c] = f;
        }
    }

    // ---- folded x-side weights: Weff = W_ih * W0 (256 x 5), pre-scaled, K=32-padded ----
    h8 Bx[4];
    #pragma unroll
    for (int q = 0; q < 4; ++q) {
        #pragma unroll
        for (int jj = 0; jj < 8; ++jj) Bx[q][jj] = (_Float16)0.0f;
    }
    if (quad == 0) {
        #pragma unroll
        for (int q = 0; q < 4; ++q) {
            const int row = q * 64 + w * 16 + col;
            #pragma unroll
            for (int jj = 0; jj < IN_F; ++jj) {
                float s = 0.0f;
                #pragma unroll
                for (int m = 0; m < D_FC; ++m)
                    s = fmaf(W_ih[row * D_FC + m], W0[m * IN_F + jj], s);
                Bx[q][jj] = (_Float16)(s * SC[q]);
            }
        }
    }

    // ---- folded bias, pre-scaled, as PERSISTENT MFMA C-operands (D!=C, no movs) ----
    f4 biasC[4];
    #pragma unroll
    for (int q = 0; q < 4; ++q) {
        const int row = q * 64 + w * 16 + col;
        float s = b_ih[row] + b_hh[row];
        #pragma unroll
        for (int m = 0; m < D_FC; ++m)
            s = fmaf(W_ih[row * D_FC + m], b0[m], s);
        const float sbq = s * SC[q];
        biasC[q] = (f4){ sbq, sbq, sbq, sbq };
    }

    const f2 pk2 = {  K2,  K2 };
    const f2 one = { 1.0f, 1.0f };

    // ---- zero both LDS H buffers (h(-1)=0) ----
    for (int i = tid; i < 2 * NROW * ROWE; i += 256)
        ((_Float16*)H)[i] = (_Float16)0.0f;

    // ---- x feed: A-frag row = batch = col (quads duplicate; cache absorbs) ----
    const float* xb = x + (size_t)(bblk + col) * T_STEPS * IN_F;

    union AxU { h8 v; h2 pk[4]; };
    AxU Ax[2];
    #pragma unroll
    for (int jj = 0; jj < 8; ++jj) { Ax[0].v[jj] = (_Float16)0.0f; Ax[1].v[jj] = (_Float16)0.0f; }
    {   // Ax[0] = x(0)
        const f4 v0 = *(const f4*)xb;
        const float s0 = xb[4];
        Ax[0].pk[0] = __builtin_amdgcn_cvt_pkrtz(v0[0], v0[1]);
        Ax[0].pk[1] = __builtin_amdgcn_cvt_pkrtz(v0[2], v0[3]);
        Ax[0].pk[2] = __builtin_amdgcn_cvt_pkrtz(s0, 0.0f);
    }
    // prefetch buffers: xv[0]=x(1), xv[1]=x(2)
    f4 xv[2]; float x4[2];
    xv[0] = *(const f4*)(xb + IN_F);      x4[0] = xb[IN_F + 4];
    xv[1] = *(const f4*)(xb + 2 * IN_F);  x4[1] = xb[2 * IN_F + 4];

    // cell state: lane owns (batch = quad*4 + r, j = w*16+col); pairs {0,1},{2,3}
    f2 cs01 = {0.0f, 0.0f}, cs23 = {0.0f, 0.0f};

    __syncthreads();    // zero-init visible

    for (int it = 0; it < T_STEPS / 2; ++it) {
        #pragma unroll
        for (int u = 0; u < 2; ++u) {
            // h(t-1) A-fragments from buffer u
            const h8 A1 = *(const h8*)&H[u][col][quad * 8];
            const h8 A2 = *(const h8*)&H[u][col][32 + quad * 8];

            // pack next-step Ax while lgkm pending; then issue x(t+3) prefetch
            Ax[u ^ 1].pk[0] = __builtin_amdgcn_cvt_pkrtz(xv[u][0], xv[u][1]);
            Ax[u ^ 1].pk[1] = __builtin_amdgcn_cvt_pkrtz(xv[u][2], xv[u][3]);
            Ax[u ^ 1].pk[2] = __builtin_amdgcn_cvt_pkrtz(x4[u], 0.0f);
            {
                int tn = 2 * it + u + 3;
                tn = (tn < T_STEPS) ? tn : (T_STEPS - 1);
                const float* xp = xb + tn * IN_F;
                xv[u] = *(const f4*)xp;     // stays in flight across barriers
                x4[u] = xp[4];
            }

            // 12 MFMAs, PHASE-MAJOR; x-phase carries the scaled bias as C-operand
            f4 acc[4];
            #pragma unroll
            for (int q = 0; q < 4; ++q)
                acc[q] = __builtin_amdgcn_mfma_f32_16x16x32_f16(Ax[u].v, Bx[q], biasC[q], 0, 0, 0);
            #pragma unroll
            for (int q = 0; q < 4; ++q)
                acc[q] = __builtin_amdgcn_mfma_f32_16x16x32_f16(A1, Bf[q][0], acc[q], 0, 0, 0);
            #pragma unroll
            for (int q = 0; q < 4; ++q)
                acc[q] = __builtin_amdgcn_mfma_f32_16x16x32_f16(A2, Bf[q][1], acc[q], 0, 0, 0);

            // elementwise LSTM: acc IS the exp2 argument; all indices literal
            lstm_cell4((f2){acc[0][0], acc[0][1]}, (f2){acc[1][0], acc[1][1]},
                       (f2){acc[2][0], acc[2][1]}, (f2){acc[3][0], acc[3][1]},
                       (f2){acc[0][2], acc[0][3]}, (f2){acc[1][2], acc[1][3]},
                       (f2){acc[2][2], acc[2][3]}, (f2){acc[3][2], acc[3][3]},
                       pk2, one, cs01, cs23,
                       &H[u ^ 1][quad * 4 + 0][w * 16 + col],
                       &H[u ^ 1][quad * 4 + 1][w * 16 + col],
                       &H[u ^ 1][quad * 4 + 2][w * 16 + col],
                       &H[u ^ 1][quad * 4 + 3][w * 16 + col]);

            // single barrier WITHOUT vmcnt drain: H writes visible, x-prefetch in flight
            asm volatile("s_waitcnt lgkmcnt(0)" ::: "memory");
            __builtin_amdgcn_s_barrier();
            asm volatile("" ::: "memory");
        }
    }

    // ---- output head: h_last lives in H[0]; batch b at row b ----
    if (tid < MB) {
        float a = bo[0];
        #pragma unroll 8
        for (int j = 0; j < D_H; ++j)
            a = fmaf((float)H[0][tid][j], Wo[j], a);
        out[bblk + tid] = a;
    }
}

extern "C" void kernel_launch(void* const* d_in, const int* in_sizes, int n_in,
                              void* d_out, int out_size, void* d_ws, size_t ws_size,
                              hipStream_t stream) {
    const float* x    = (const float*)d_in[0];
    const float* W0   = (const float*)d_in[1];
    const float* b0   = (const float*)d_in[2];
    const float* W_ih = (const float*)d_in[3];
    const float* W_hh = (const float*)d_in[4];
    const float* b_ih = (const float*)d_in[5];
    const float* b_hh = (const float*)d_in[6];
    const float* Wo   = (const float*)d_in[7];
    const float* bo   = (const float*)d_in[8];
    float* out = (float*)d_out;

    hipLaunchKernelGGL(lstm_mfma, dim3(B_TOT / MB), dim3(256), 0, stream,
                       x, W0, b0, W_ih, W_hh, b_ih, b_hh, Wo, bo, out);
}

// Round 12
// 282.701 us; speedup vs baseline: 1.4957x; 1.0024x over previous
//
#include <hip/hip_runtime.h>

#define B_TOT   4096
#define T_STEPS 512
#define IN_F    5
#define D_FC    32
#define D_H     64
#define MB      16      // batches per block; DENSE M-tile: batch b = A-row b
#define NROW    16
#define ROWE    72      // f16 elems per row (64 h + 8 pad; 144B rows, 16B-aligned)

typedef _Float16 h8 __attribute__((ext_vector_type(8)));
typedef __fp16   h2 __attribute__((ext_vector_type(2)));
typedef float    f4 __attribute__((ext_vector_type(4)));
typedef float    f2 __attribute__((ext_vector_type(2)));

__device__ __forceinline__ float fexp2(float x) { return __builtin_amdgcn_exp2f(x); }
__device__ __forceinline__ float frcp(float x)  { return __builtin_amdgcn_rcpf(x); }

#define MFMA16(A, B, C) __builtin_amdgcn_mfma_f32_16x16x32_f16((A), (B), (C), 0, 0, 0)

__global__ __launch_bounds__(256) void lstm_mfma(
    const float* __restrict__ x,
    const float* __restrict__ W0,
    const float* __restrict__ b0,
    const float* __restrict__ W_ih,
    const float* __restrict__ W_hh,
    const float* __restrict__ b_ih,
    const float* __restrict__ b_hh,
    const float* __restrict__ Wo,
    const float* __restrict__ bo,
    float* __restrict__ out)
{
    // double-buffered h(t-1), f16: H[buf][batch-row][hidden]
    __shared__ __align__(16) _Float16 H[2][NROW][ROWE];

    const int tid  = threadIdx.x;
    const int lane = tid & 63;
    const int w    = tid >> 6;      // wave id: owns hidden j in [w*16, w*16+16)
    const int col  = lane & 15;
    const int quad = lane >> 4;
    const int bblk = blockIdx.x * MB;

    const float K1 = 1.4426950408889634f;   // log2(e)
    const float K2 = 2.8853900817779268f;   // 2*log2(e)
    // per-gate pre-scale: i,f,o -> -log2(e); g -> +2*log2(e)
    const float SC[4] = { -K1, -K1, K2, -K1 };

    // ---- resident W_hh B-fragments, PRE-SCALED per gate; named (no arrays) ----
    h8 Bf00, Bf01, Bf10, Bf11, Bf20, Bf21, Bf30, Bf31;
    {
        h8 tmp[4][2];
        #pragma unroll
        for (int q = 0; q < 4; ++q) {
            const int row = q * 64 + w * 16 + col;
            #pragma unroll
            for (int c = 0; c < 2; ++c) {
                h8 f;
                #pragma unroll
                for (int jj = 0; jj < 8; ++jj) {
                    const int k = c * 32 + quad * 8 + jj;
                    f[jj] = (_Float16)(W_hh[row * D_H + k] * SC[q]);
                }
                tmp[q][c] = f;
            }
        }
        Bf00 = tmp[0][0]; Bf01 = tmp[0][1];
        Bf10 = tmp[1][0]; Bf11 = tmp[1][1];
        Bf20 = tmp[2][0]; Bf21 = tmp[2][1];
        Bf30 = tmp[3][0]; Bf31 = tmp[3][1];
    }

    // ---- folded x-side weights: Weff = W_ih * W0 (256 x 5), pre-scaled, K=32-padded ----
    h8 Bx0, Bx1, Bx2, Bx3;
    {
        h8 tmp[4];
        #pragma unroll
        for (int q = 0; q < 4; ++q) {
            #pragma unroll
            for (int jj = 0; jj < 8; ++jj) tmp[q][jj] = (_Float16)0.0f;
        }
        if (quad == 0) {
            #pragma unroll
            for (int q = 0; q < 4; ++q) {
                const int row = q * 64 + w * 16 + col;
                #pragma unroll
                for (int jj = 0; jj < IN_F; ++jj) {
                    float s = 0.0f;
                    #pragma unroll
                    for (int m = 0; m < D_FC; ++m)
                        s = fmaf(W_ih[row * D_FC + m], W0[m * IN_F + jj], s);
                    tmp[q][jj] = (_Float16)(s * SC[q]);
                }
            }
        }
        Bx0 = tmp[0]; Bx1 = tmp[1]; Bx2 = tmp[2]; Bx3 = tmp[3];
    }

    // ---- folded bias, pre-scaled, as PERSISTENT MFMA C-operands ----
    f4 biasC0, biasC1, biasC2, biasC3;
    {
        f4 tmp[4];
        #pragma unroll
        for (int q = 0; q < 4; ++q) {
            const int row = q * 64 + w * 16 + col;
            float s = b_ih[row] + b_hh[row];
            #pragma unroll
            for (int m = 0; m < D_FC; ++m)
                s = fmaf(W_ih[row * D_FC + m], b0[m], s);
            const float sbq = s * SC[q];
            tmp[q] = (f4){ sbq, sbq, sbq, sbq };
        }
        biasC0 = tmp[0]; biasC1 = tmp[1]; biasC2 = tmp[2]; biasC3 = tmp[3];
    }

    const f2 pk2 = {  K2,  K2 };
    const f2 one = { 1.0f, 1.0f };

    // ---- zero both LDS H buffers (h(-1)=0) ----
    for (int i = tid; i < 2 * NROW * ROWE; i += 256)
        ((_Float16*)H)[i] = (_Float16)0.0f;

    // ---- x feed: A-frag row = batch = col (quads duplicate; cache absorbs) ----
    const float* xb = x + (size_t)(bblk + col) * T_STEPS * IN_F;

    union AxU { h8 v; h2 pk[4]; };
    AxU Ax[2];
    #pragma unroll
    for (int jj = 0; jj < 8; ++jj) { Ax[0].v[jj] = (_Float16)0.0f; Ax[1].v[jj] = (_Float16)0.0f; }
    {   // Ax[0] = x(0)
        const f4 v0 = *(const f4*)xb;
        const float s0 = xb[4];
        Ax[0].pk[0] = __builtin_amdgcn_cvt_pkrtz(v0[0], v0[1]);
        Ax[0].pk[1] = __builtin_amdgcn_cvt_pkrtz(v0[2], v0[3]);
        Ax[0].pk[2] = __builtin_amdgcn_cvt_pkrtz(s0, 0.0f);
    }
    // prefetch buffers: xv[0]=x(1), xv[1]=x(2)
    f4 xv[2]; float x4[2];
    xv[0] = *(const f4*)(xb + IN_F);      x4[0] = xb[IN_F + 4];
    xv[1] = *(const f4*)(xb + 2 * IN_F);  x4[1] = xb[2 * IN_F + 4];

    // cell state: lane owns (batch = quad*4 + r, j = w*16+col); pairs {0,1},{2,3}
    f2 cs01 = {0.0f, 0.0f}, cs23 = {0.0f, 0.0f};

    __syncthreads();    // zero-init visible

    for (int it = 0; it < T_STEPS / 2; ++it) {
        #pragma unroll
        for (int u = 0; u < 2; ++u) {
            // h(t-1) A-fragments from buffer u
            const h8 A1 = *(const h8*)&H[u][col][quad * 8];
            const h8 A2 = *(const h8*)&H[u][col][32 + quad * 8];

            // pack next-step Ax while lgkm pending; then issue x(t+3) prefetch
            Ax[u ^ 1].pk[0] = __builtin_amdgcn_cvt_pkrtz(xv[u][0], xv[u][1]);
            Ax[u ^ 1].pk[1] = __builtin_amdgcn_cvt_pkrtz(xv[u][2], xv[u][3]);
            Ax[u ^ 1].pk[2] = __builtin_amdgcn_cvt_pkrtz(x4[u], 0.0f);
            {
                int tn = 2 * it + u + 3;
                tn = (tn < T_STEPS) ? tn : (T_STEPS - 1);
                const float* xp = xb + tn * IN_F;
                xv[u] = *(const f4*)xp;     // stays in flight across barriers
                x4[u] = xp[4];
            }

            // x-phase (register operands, bias as C): covers ds_read latency
            f4 acc0 = MFMA16(Ax[u].v, Bx0, biasC0);
            f4 acc1 = MFMA16(Ax[u].v, Bx1, biasC1);
            f4 acc2 = MFMA16(Ax[u].v, Bx2, biasC2);
            f4 acc3 = MFMA16(Ax[u].v, Bx3, biasC3);
            // finish gates i,f FIRST (cs-critical chain)
            acc0 = MFMA16(A1, Bf00, acc0);
            acc1 = MFMA16(A1, Bf10, acc1);
            acc0 = MFMA16(A2, Bf01, acc0);
            acc1 = MFMA16(A2, Bf11, acc1);
            // q=2,3 A1-phase issues on the matrix pipe...
            acc2 = MFMA16(A1, Bf20, acc2);
            acc3 = MFMA16(A1, Bf30, acc3);

            // ...while i,f exp2 start on the trans pipe (acc0/acc1 complete)
            f2 EiA, EiB, EfA, EfB;
            EiA[0]=fexp2(acc0[0]); EiA[1]=fexp2(acc0[1]);
            EiB[0]=fexp2(acc0[2]); EiB[1]=fexp2(acc0[3]);
            EfA[0]=fexp2(acc1[0]); EfA[1]=fexp2(acc1[1]);
            EfB[0]=fexp2(acc1[2]); EfB[1]=fexp2(acc1[3]);

            acc2 = MFMA16(A2, Bf21, acc2);
            acc3 = MFMA16(A2, Bf31, acc3);

            // g,o exp2 (o is off the cs chain — ordered after g)
            f2 EgA, EgB, EoA, EoB;
            EgA[0]=fexp2(acc2[0]); EgA[1]=fexp2(acc2[1]);
            EgB[0]=fexp2(acc2[2]); EgB[1]=fexp2(acc2[3]);
            EoA[0]=fexp2(acc3[0]); EoA[1]=fexp2(acc3[1]);
            EoB[0]=fexp2(acc3[2]); EoB[1]=fexp2(acc3[3]);

            // packed tail:  cs' = [cs*pI*pG + (Eg-1)*pF] / (pI*pG*pF)
            const f2 pIA = one + EiA, pFA = one + EfA, pGA = one + EgA, pOA = one + EoA;
            const f2 pIB = one + EiB, pFB = one + EfB, pGB = one + EgB, pOB = one + EoB;
            const f2 mIGA = pIA * pGA;
            const f2 mIGB = pIB * pGB;
            const f2 numA = cs01 * mIGA + (EgA - one) * pFA;
            const f2 numB = cs23 * mIGB + (EgB - one) * pFB;
            const f2 denA = mIGA * pFA;
            const f2 denB = mIGB * pFB;
            f2 rA, rB;
            rA[0] = frcp(denA[0]); rA[1] = frcp(denA[1]);
            rB[0] = frcp(denB[0]); rB[1] = frcp(denB[1]);
            cs01 = numA * rA;
            cs23 = numB * rB;
            const f2 aCA = pk2 * cs01;
            const f2 aCB = pk2 * cs23;
            f2 EcA, EcB;
            EcA[0]=fexp2(aCA[0]); EcA[1]=fexp2(aCA[1]);
            EcB[0]=fexp2(aCB[0]); EcB[1]=fexp2(aCB[1]);
            const f2 mOCA = pOA * (one + EcA);
            const f2 mOCB = pOB * (one + EcB);
            f2 r2A, r2B;
            r2A[0] = frcp(mOCA[0]); r2A[1] = frcp(mOCA[1]);
            r2B[0] = frcp(mOCB[0]); r2B[1] = frcp(mOCB[1]);
            const f2 hA = (EcA - one) * r2A;
            const f2 hB = (EcB - one) * r2B;
            H[u ^ 1][quad * 4 + 0][w * 16 + col] = (_Float16)hA[0];
            H[u ^ 1][quad * 4 + 1][w * 16 + col] = (_Float16)hA[1];
            H[u ^ 1][quad * 4 + 2][w * 16 + col] = (_Float16)hB[0];
            H[u ^ 1][quad * 4 + 3][w * 16 + col] = (_Float16)hB[1];

            // single barrier WITHOUT vmcnt drain: H writes visible, x-prefetch in flight
            asm volatile("s_waitcnt lgkmcnt(0)" ::: "memory");
            __builtin_amdgcn_s_barrier();
            asm volatile("" ::: "memory");
        }
    }

    // ---- output head: h_last lives in H[0]; batch b at row b ----
    if (tid < MB) {
        float a = bo[0];
        #pragma unroll 8
        for (int j = 0; j < D_H; ++j)
            a = fmaf((float)H[0][tid][j], Wo[j], a);
        out[bblk + tid] = a;
    }
}

extern "C" void kernel_launch(void* const* d_in, const int* in_sizes, int n_in,
                              void* d_out, int out_size, void* d_ws, size_t ws_size,
                              hipStream_t stream) {
    const float* x    = (const float*)d_in[0];
    const float* W0   = (const float*)d_in[1];
    const float* b0   = (const float*)d_in[2];
    const float* W_ih = (const float*)d_in[3];
    const float* W_hh = (const float*)d_in[4];
    const float* b_ih = (const float*)d_in[5];
    const float* b_hh = (const float*)d_in[6];
    const float* Wo   = (const float*)d_in[7];
    const float* bo   = (const float*)d_in[8];
    float* out = (float*)d_out;

    hipLaunchKernelGGL(lstm_mfma, dim3(B_TOT / MB), dim3(256), 0, stream,
                       x, W0, b0, W_ih, W_hh, b_ih, b_hh, Wo, bo, out);
}